// Round 8
// baseline (265.121 us; speedup 1.0000x reference)
//
#include <hip/hip_runtime.h>
#include <hip/hip_fp16.h>

// ResidualDenoiser: 4 chained GEMMs + BN/ReLU + ragged segment softmax.
// Activations live in one persistent fp16 buffer H[8192][3328] laid out
// [A3 | A2 | A1 | A0=x] so each layer's concatenated input is H + colOff.
//   layer0: in H+3072 (K= 256) -> out cols 2048:3072
//   layer1: in H+2048 (K=1280) -> out cols 1024:2048
//   layer2: in H+1024 (K=2304) -> out cols    0:1024
//   layer3: in H+0    (K=3328) -> splitK=4 atomicAdd fp32 into out (bias
//           pre-applied by prep), then separate segment-softmax dispatch.
// LESSONS (measured):
//  - R4/R5/R6: in-kernel cross-block sync (grid barriers, last-arriver
//    counters, agent fences) costs 300-450 us on this 8-XCD part — dispatch
//    boundaries ARE the cheap sync. Keep separate dispatches.
//  - R7: BK=128 gained nothing (and 4.7M LDS bank conflicts); the ~50 us/
//    layer plateau is the serialized sum of MFMA-issue + LDS-read + L2-
//    staging floors, not barrier count. BK=64 staging restored.
//  - R8: use 32x32x16 MFMA (m119: 2495 vs 2075 TF) — same LDS traffic,
//    ~20% better matrix-pipe efficiency, half the instruction count.
// GEMM tile: BM=BN=128, BK=64, 4 waves (2x2) each 64x64 (2x2 of 32x32).

#define LDH 3328
#define NROWS 8192

typedef _Float16 f16x8 __attribute__((ext_vector_type(8)));
typedef _Float16 f16x4 __attribute__((ext_vector_type(4)));
typedef float f32x16 __attribute__((ext_vector_type(16)));

__constant__ int c_bnd[11] = {0, 2, 5, 10, 18, 31, 52, 86, 141, 230, 256};

// async global->LDS, 16B per lane; LDS dest is wave-uniform base + lane*16.
__device__ __forceinline__ void async_cp16(const _Float16* g, _Float16* l) {
  __builtin_amdgcn_global_load_lds(
      (__attribute__((address_space(1))) void*)g,
      (__attribute__((address_space(3))) void*)l, 16, 0, 0);
}

__device__ __forceinline__ _Float16 f2h(float f) { return (_Float16)f; }

// ---------------------------------------------------------------------------
// prep: weights fp32->fp16 (contiguous), x staged into H, out = bias.
__global__ void prep_kernel(const float* __restrict__ s0,
                            const float* __restrict__ s1,
                            const float* __restrict__ s2,
                            const float* __restrict__ s3,
                            const float* __restrict__ x,
                            const float* __restrict__ b3,
                            _Float16* __restrict__ d0,
                            _Float16* __restrict__ d1,
                            _Float16* __restrict__ d2,
                            _Float16* __restrict__ d3,
                            _Float16* __restrict__ H, float* __restrict__ out,
                            int n0, int n1, int n2, int n3, int n4, int n5) {
  int i = blockIdx.x * blockDim.x + threadIdx.x;
  if (i >= n5) return;
  if (i >= n4) {  // out[8192][256] = broadcast bias b3
    const int j = i - n4;
    const int c = (j & 63) * 4;
    *(float4*)&out[(size_t)j * 4] = *(const float4*)&b3[c];
    return;
  }
  if (i >= n3) {  // x[8192,256] -> H[:, 3072:3328]
    const int j = i - n3;
    const int row = j >> 6;
    const int c = (j & 63) * 4;
    const float4 v = *(const float4*)&x[(size_t)j * 4];
    f16x4 h = {f2h(v.x), f2h(v.y), f2h(v.z), f2h(v.w)};
    *(f16x4*)&H[(size_t)row * LDH + 3072 + c] = h;
    return;
  }
  const float* s;
  _Float16* d;
  if (i < n0) {
    s = s0; d = d0;
  } else if (i < n1) {
    s = s1 - (size_t)n0 * 4; d = d1 - (size_t)n0 * 4;
  } else if (i < n2) {
    s = s2 - (size_t)n1 * 4; d = d2 - (size_t)n1 * 4;
  } else {
    s = s3 - (size_t)n2 * 4; d = d3 - (size_t)n2 * 4;
  }
  const float4 v = *(const float4*)&s[(size_t)i * 4];
  f16x4 h = {f2h(v.x), f2h(v.y), f2h(v.z), f2h(v.w)};
  *(f16x4*)&d[(size_t)i * 4] = h;
}

// ---------------------------------------------------------------------------
// Layers 0-2: C = relu(bn(A[128,K] @ W[128,K]^T)) -> fp16 into H.
// Grid dim3(64,8). BK=64 staging (R2's proven pattern, 0 bank conflicts).
// Compute: 32x32x16 MFMA, per wave 2x2 tiles of 32x32.
__launch_bounds__(256, 4) __global__
void gemm_bn_kernel(const _Float16* __restrict__ A, int K,
                    const _Float16* __restrict__ W,
                    const float* __restrict__ bias,
                    const float* __restrict__ g, const float* __restrict__ be,
                    const float* __restrict__ rm,
                    const float* __restrict__ rv, _Float16* __restrict__ outH,
                    int outOff) {
  __shared__ _Float16 Alds[128 * 64];
  __shared__ _Float16 Blds[128 * 64];

  const int tid = threadIdx.x;
  const int lane = tid & 63;
  const int wave = tid >> 6;          // 0..3
  const int wr = wave >> 1;           // 64-row half
  const int wc = wave & 1;            // 64-col half
  const int row0 = blockIdx.x * 128;  // M block
  const int col0 = blockIdx.y * 128;  // N block
  // staging lane decomposition: 8 rows x 8 chunks(16B) per wave-instruction
  const int lr = lane >> 3;  // row within 8-row group
  const int ls = lane & 7;   // lds slot within row
  const int lc = ls ^ lr;    // XOR-swizzle: global chunk fetched into slot ls
  // fragment lane decomposition (32x32x16 MFMA)
  const int fm = lane & 31;  // m (A) / n (B) index
  const int hk = lane >> 5;  // k-half: k = ks*16 + hk*8 + j

  f32x16 acc[2][2] = {};

  for (int k0 = 0; k0 < K; k0 += 64) {
    __syncthreads();  // previous-iter consumers done before overwrite
#pragma unroll
    for (int it = 0; it < 4; ++it) {
      const int rl = it * 32 + wave * 8;
      async_cp16(A + (size_t)(row0 + rl + lr) * LDH + k0 + lc * 8,
                 &Alds[rl * 64]);
      async_cp16(W + (size_t)(col0 + rl + lr) * K + k0 + lc * 8,
                 &Blds[rl * 64]);
    }
    __syncthreads();  // drains vmcnt: staging complete

#pragma unroll
    for (int ks = 0; ks < 4; ++ks) {  // K=16 slices
      f16x8 av[2], bv[2];
#pragma unroll
      for (int t = 0; t < 2; ++t) {
        const int ra = wr * 64 + t * 32 + fm;
        av[t] =
            *(const f16x8*)&Alds[ra * 64 + (((ks * 2 + hk) ^ (ra & 7)) * 8)];
        const int rb = wc * 64 + t * 32 + fm;
        bv[t] =
            *(const f16x8*)&Blds[rb * 64 + (((ks * 2 + hk) ^ (rb & 7)) * 8)];
      }
#pragma unroll
      for (int tm = 0; tm < 2; ++tm)
#pragma unroll
        for (int tn = 0; tn < 2; ++tn)
          acc[tm][tn] = __builtin_amdgcn_mfma_f32_32x32x16_f16(
              av[tm], bv[tn], acc[tm][tn], 0, 0, 0);
    }
  }

  // Epilogue. 32x32 C/D: col = lane&31, row = (reg&3) + 8*(reg>>2) + 4*hk.
#pragma unroll
  for (int tn = 0; tn < 2; ++tn) {
    const int n = col0 + wc * 64 + tn * 32 + fm;
    const float alpha = g[n] * rsqrtf(rv[n] + 1e-5f);
    const float beta = (bias[n] - rm[n]) * alpha + be[n];
#pragma unroll
    for (int tm = 0; tm < 2; ++tm) {
      const int rbase = row0 + wr * 64 + tm * 32 + 4 * hk;
#pragma unroll
      for (int reg = 0; reg < 16; ++reg) {
        const int row = rbase + (reg & 3) + 8 * (reg >> 2);
        float v = acc[tm][tn][reg] * alpha + beta;
        v = fmaxf(v, 0.0f);
        outH[(size_t)row * LDH + outOff + n] = f2h(v);
      }
    }
  }
}

// ---------------------------------------------------------------------------
// Layer 3: splitK=4, BK=64 (832 = 13*64 per slice). Grid dim3(64,8):
// cb=by&1 (col tile), ks=by>>1. Partials atomicAdd into out (bias
// pre-applied by prep). 32x32x16 MFMA.
__launch_bounds__(256, 4) __global__
void gemm_out_kernel(const _Float16* __restrict__ A,
                     const _Float16* __restrict__ W,
                     float* __restrict__ out) {
  __shared__ _Float16 Alds[128 * 64];
  __shared__ _Float16 Blds[128 * 64];

  const int tid = threadIdx.x;
  const int lane = tid & 63;
  const int wave = tid >> 6;
  const int wr = wave >> 1;
  const int wc = wave & 1;
  const int row0 = blockIdx.x * 128;
  const int cb = blockIdx.y & 1;
  const int ksl = blockIdx.y >> 1;
  const int col0 = cb * 128;
  const int k0b = ksl * 832;
  const int k0e = k0b + 832;
  const int lr = lane >> 3;
  const int ls = lane & 7;
  const int lc = ls ^ lr;
  const int fm = lane & 31;
  const int hk = lane >> 5;
  const int K = 3328;

  f32x16 acc[2][2] = {};

  for (int k0 = k0b; k0 < k0e; k0 += 64) {
    __syncthreads();
#pragma unroll
    for (int it = 0; it < 4; ++it) {
      const int rl = it * 32 + wave * 8;
      async_cp16(A + (size_t)(row0 + rl + lr) * LDH + k0 + lc * 8,
                 &Alds[rl * 64]);
      async_cp16(W + (size_t)(col0 + rl + lr) * K + k0 + lc * 8,
                 &Blds[rl * 64]);
    }
    __syncthreads();

#pragma unroll
    for (int ks = 0; ks < 4; ++ks) {
      f16x8 av[2], bv[2];
#pragma unroll
      for (int t = 0; t < 2; ++t) {
        const int ra = wr * 64 + t * 32 + fm;
        av[t] =
            *(const f16x8*)&Alds[ra * 64 + (((ks * 2 + hk) ^ (ra & 7)) * 8)];
        const int rb = wc * 64 + t * 32 + fm;
        bv[t] =
            *(const f16x8*)&Blds[rb * 64 + (((ks * 2 + hk) ^ (rb & 7)) * 8)];
      }
#pragma unroll
      for (int tm = 0; tm < 2; ++tm)
#pragma unroll
        for (int tn = 0; tn < 2; ++tn)
          acc[tm][tn] = __builtin_amdgcn_mfma_f32_32x32x16_f16(
              av[tm], bv[tn], acc[tm][tn], 0, 0, 0);
    }
  }

#pragma unroll
  for (int tn = 0; tn < 2; ++tn) {
    const int n = col0 + wc * 64 + tn * 32 + fm;
#pragma unroll
    for (int tm = 0; tm < 2; ++tm) {
      const int rbase = row0 + wr * 64 + tm * 32 + 4 * hk;
#pragma unroll
      for (int reg = 0; reg < 16; ++reg) {
        const int row = rbase + (reg & 3) + 8 * (reg >> 2);
        atomicAdd(&out[(size_t)row * 256 + n], acc[tm][tn][reg]);
      }
    }
  }
}

// ---------------------------------------------------------------------------
// ragged segment softmax, in place on out[8192][256]; 4 rows/block (1/wave).
__global__ void segsoftmax_kernel(float* __restrict__ out,
                                  const int* __restrict__ segids) {
  __shared__ float vals[4][256];
  __shared__ float red[4][10];
  const int w = threadIdx.x >> 6;
  const int l = threadIdx.x & 63;
  const int row = blockIdx.x * 4 + w;
  float4 v = *(float4*)&out[(size_t)row * 256 + l * 4];
  *(float4*)&vals[w][l * 4] = v;
  __syncthreads();
  if (l < 10) {
    float m = -1e30f;
    for (int j = c_bnd[l]; j < c_bnd[l + 1]; ++j) m = fmaxf(m, vals[w][j]);
    red[w][l] = m;
  }
  __syncthreads();
  const int4 s4 = *(const int4*)&segids[l * 4];
  float4 e;
  e.x = expf(v.x - red[w][s4.x]);
  e.y = expf(v.y - red[w][s4.y]);
  e.z = expf(v.z - red[w][s4.z]);
  e.w = expf(v.w - red[w][s4.w]);
  *(float4*)&vals[w][l * 4] = e;
  __syncthreads();
  if (l < 10) {
    float s = 0.0f;
    for (int j = c_bnd[l]; j < c_bnd[l + 1]; ++j) s += vals[w][j];
    red[w][l] = s;
  }
  __syncthreads();
  float4 o;
  o.x = e.x / red[w][s4.x];
  o.y = e.y / red[w][s4.y];
  o.z = e.z / red[w][s4.z];
  o.w = e.w / red[w][s4.w];
  *(float4*)&out[(size_t)row * 256 + l * 4] = o;
}

// ---------------------------------------------------------------------------
extern "C" void kernel_launch(void* const* d_in, const int* in_sizes, int n_in,
                              void* d_out, int out_size, void* d_ws,
                              size_t ws_size, hipStream_t stream) {
  const float* x = (const float*)d_in[0];
  const float* W0 = (const float*)d_in[1];
  const float* b0 = (const float*)d_in[2];
  const float* g0 = (const float*)d_in[3];
  const float* be0 = (const float*)d_in[4];
  const float* rm0 = (const float*)d_in[5];
  const float* rv0 = (const float*)d_in[6];
  const float* W1 = (const float*)d_in[7];
  const float* b1 = (const float*)d_in[8];
  const float* g1 = (const float*)d_in[9];
  const float* be1 = (const float*)d_in[10];
  const float* rm1 = (const float*)d_in[11];
  const float* rv1 = (const float*)d_in[12];
  const float* W2 = (const float*)d_in[13];
  const float* b2 = (const float*)d_in[14];
  const float* g2 = (const float*)d_in[15];
  const float* be2 = (const float*)d_in[16];
  const float* rm2 = (const float*)d_in[17];
  const float* rv2 = (const float*)d_in[18];
  const float* W3 = (const float*)d_in[19];
  const float* b3 = (const float*)d_in[20];
  const int* seg = (const int*)d_in[21];
  float* out = (float*)d_out;

  // ws (fp16): H[8192*3328] | Wh0 | Wh1 | Wh2 | Wh3  (~64.1 MB)
  _Float16* H = (_Float16*)d_ws;
  size_t off = (size_t)NROWS * LDH;
  _Float16* Wh0 = H + off; off += 1024 * 256;
  _Float16* Wh1 = H + off; off += 1024 * 1280;
  _Float16* Wh2 = H + off; off += 1024 * 2304;
  _Float16* Wh3 = H + off;

  // cumulative float4 counts: W0, W1, W2, W3, x, out-init
  const int n0 = 65536, n1 = n0 + 327680, n2 = n1 + 589824, n3 = n2 + 212992;
  const int n4 = n3 + 524288, n5 = n4 + 524288;
  prep_kernel<<<(n5 + 255) / 256, 256, 0, stream>>>(
      W0, W1, W2, W3, x, b3, Wh0, Wh1, Wh2, Wh3, H, out, n0, n1, n2, n3, n4,
      n5);

  dim3 blk(256);
  gemm_bn_kernel<<<dim3(64, 8), blk, 0, stream>>>(
      H + 3072, 256, Wh0, b0, g0, be0, rm0, rv0, H, 2048);
  gemm_bn_kernel<<<dim3(64, 8), blk, 0, stream>>>(
      H + 2048, 1280, Wh1, b1, g1, be1, rm1, rv1, H, 1024);
  gemm_bn_kernel<<<dim3(64, 8), blk, 0, stream>>>(
      H + 1024, 2304, Wh2, b2, g2, be2, rm2, rv2, H, 0);
  gemm_out_kernel<<<dim3(64, 8), blk, 0, stream>>>(H, Wh3, out);
  segsoftmax_kernel<<<2048, 256, 0, stream>>>(out, seg);
}

// Round 9
// 253.565 us; speedup vs baseline: 1.0456x; 1.0456x over previous
//
#include <hip/hip_runtime.h>
#include <hip/hip_fp16.h>

// ResidualDenoiser: 4 chained GEMMs + BN/ReLU + ragged segment softmax.
// Activations live in one persistent fp16 buffer H[8192][3328] laid out
// [A3 | A2 | A1 | A0=x] so each layer's concatenated input is H + colOff.
//   layer0: A = x fp32 (cvt-staged in-kernel), W0 fp32 (cvt-staged in-kernel)
//           -> out cols 2048:3072; by==0 blocks write cvt'd x to cols 3072:.
//           Side-work: cvt W1/W2/W3 -> fp16, out = bias b3 (grid-stride).
//   layer1: in H+2048 (K=1280) -> out cols 1024:2048
//   layer2: in H+1024 (K=2304) -> out cols    0:1024
//   layer3: in H+0    (K=3328) -> splitK=4 atomicAdd fp32 into out, then
//           separate segment-softmax dispatch.
// LESSONS (measured):
//  - R4/R5/R6: in-kernel cross-block sync costs 300-450 us on this 8-XCD
//    part — dispatch boundaries ARE the cheap sync. But each boundary costs
//    ~15-20 us of gap -> fold prep into L0 as side-work (no sync needed:
//    consumers are later dispatches). 6 -> 5 dispatches.
//  - R7: BK=128 regressed (4.7M LDS conflicts). R8: 32x32x16 MFMA regressed
//    (same 4.7M conflicts: 32-row frag reads alias 4-bank groups 8-way).
//    16x16x32 + BK=64 + XOR swizzle is the only 0-conflict config. Keep it.
// GEMM tile: BM=BN=128, BK=64, 4 waves (2x2) each 64x64, 16x16x32 f16 MFMA.

#define LDH 3328
#define NROWS 8192

typedef _Float16 f16x8 __attribute__((ext_vector_type(8)));
typedef _Float16 f16x4 __attribute__((ext_vector_type(4)));
typedef float f32x4 __attribute__((ext_vector_type(4)));

__constant__ int c_bnd[11] = {0, 2, 5, 10, 18, 31, 52, 86, 141, 230, 256};

// async global->LDS, 16B per lane; LDS dest is wave-uniform base + lane*16.
__device__ __forceinline__ void async_cp16(const _Float16* g, _Float16* l) {
  __builtin_amdgcn_global_load_lds(
      (__attribute__((address_space(1))) void*)g,
      (__attribute__((address_space(3))) void*)l, 16, 0, 0);
}

__device__ __forceinline__ _Float16 f2h(float f) { return (_Float16)f; }

__device__ __forceinline__ f16x8 cvt8(const float* p) {
  const float4 a = *(const float4*)p;
  const float4 b = *(const float4*)(p + 4);
  f16x8 h = {f2h(a.x), f2h(a.y), f2h(a.z), f2h(a.w),
             f2h(b.x), f2h(b.y), f2h(b.z), f2h(b.w)};
  return h;
}

// ---------------------------------------------------------------------------
// Layer 0 (fused ex-prep): C = relu(bn(x[128,256] @ W0[128,256]^T)) -> H cols
// 2048:3072. A and W0 are fp32: cvt-staged into LDS (float4 loads -> cvt ->
// contiguous ds_write_b128; XOR swizzle applied to the GLOBAL chunk index so
// LDS layout matches the cp16 kernels). by==0 blocks write converted x tiles
// through to H cols 3072:3328 for layers 1-3. After the epilogue, grid-stride
// side-work converts W1/W2/W3 to fp16 and initializes out = bias b3.
__launch_bounds__(256, 4) __global__
void l0_kernel(const float* __restrict__ x, const float* __restrict__ W0f,
               const float* __restrict__ bias, const float* __restrict__ g,
               const float* __restrict__ be, const float* __restrict__ rm,
               const float* __restrict__ rv, const float* __restrict__ W1f,
               const float* __restrict__ W2f, const float* __restrict__ W3f,
               const float* __restrict__ b3, _Float16* __restrict__ H,
               _Float16* __restrict__ Wh1, _Float16* __restrict__ Wh2,
               _Float16* __restrict__ Wh3, float* __restrict__ out) {
  __shared__ _Float16 Alds[128 * 64];
  __shared__ _Float16 Blds[128 * 64];

  const int tid = threadIdx.x;
  const int lane = tid & 63;
  const int wave = tid >> 6;          // 0..3
  const int wr = wave >> 1;           // 64-row half
  const int wc = wave & 1;            // 64-col half
  const int row0 = blockIdx.x * 128;  // M block
  const int col0 = blockIdx.y * 128;  // N block
  // cvt-staging decomposition: 256 threads = 32 rows x 8 slots per iter
  const int sr = tid >> 3;  // row within 32-row group
  const int sl = tid & 7;   // lds 16B-slot within row
  // fragment lane decomposition (16x16x32 MFMA)
  const int fr = lane & 15;
  const int q = lane >> 4;
  const bool wthru = (blockIdx.y == 0);

  f32x4 acc[4][4] = {};

#pragma unroll 1
  for (int k0 = 0; k0 < 256; k0 += 64) {
    __syncthreads();
#pragma unroll
    for (int it = 0; it < 4; ++it) {
      const int r = it * 32 + sr;
      const int gc = sl ^ (r & 7);  // global chunk stored at slot sl
      const f16x8 ah = cvt8(&x[(size_t)(row0 + r) * 256 + k0 + gc * 8]);
      *(f16x8*)&Alds[r * 64 + sl * 8] = ah;
      if (wthru)
        *(f16x8*)&H[(size_t)(row0 + r) * LDH + 3072 + k0 + gc * 8] = ah;
      const f16x8 bh = cvt8(&W0f[(size_t)(col0 + r) * 256 + k0 + gc * 8]);
      *(f16x8*)&Blds[r * 64 + sl * 8] = bh;
    }
    __syncthreads();

#pragma unroll
    for (int kq = 0; kq < 2; ++kq) {
      f16x8 av[4], bv[4];
#pragma unroll
      for (int t = 0; t < 4; ++t) {
        const int ra = wr * 64 + t * 16 + fr;
        av[t] = *(const f16x8*)&Alds[ra * 64 + (((q + 4 * kq) ^ (ra & 7)) * 8)];
        const int rb = wc * 64 + t * 16 + fr;
        bv[t] = *(const f16x8*)&Blds[rb * 64 + (((q + 4 * kq) ^ (rb & 7)) * 8)];
      }
#pragma unroll
      for (int tm = 0; tm < 4; ++tm)
#pragma unroll
        for (int tn = 0; tn < 4; ++tn)
          acc[tm][tn] = __builtin_amdgcn_mfma_f32_16x16x32_f16(
              av[tm], bv[tn], acc[tm][tn], 0, 0, 0);
    }
  }

  // Epilogue. C/D layout: col = lane&15, row = (lane>>4)*4 + reg.
#pragma unroll
  for (int tn = 0; tn < 4; ++tn) {
    const int n = col0 + wc * 64 + tn * 16 + fr;
    const float alpha = g[n] * rsqrtf(rv[n] + 1e-5f);
    const float beta = (bias[n] - rm[n]) * alpha + be[n];
#pragma unroll
    for (int tm = 0; tm < 4; ++tm) {
      const int rbase = row0 + wr * 64 + tm * 16 + q * 4;
#pragma unroll
      for (int r = 0; r < 4; ++r) {
        float v = acc[tm][tn][r] * alpha + beta;
        v = fmaxf(v, 0.0f);
        H[(size_t)(rbase + r) * LDH + 2048 + n] = f2h(v);
      }
    }
  }

  // ---- side-work for later dispatches (no sync needed: consumers are in
  // later kernels; the dispatch boundary is the sync). float4-group counts:
  // W1 327680 | W2 589824 | W3 212992 | out-init 524288.
  const int c1 = 327680, c2 = c1 + 589824, c3 = c2 + 212992;
  const int c4 = c3 + 524288;
  const int bid = blockIdx.y * 64 + blockIdx.x;  // 0..511
  for (int i = bid * 256 + tid; i < c4; i += 512 * 256) {
    if (i < c3) {
      const float* s;
      _Float16* d;
      int j;
      if (i < c1) {
        s = W1f; d = Wh1; j = i;
      } else if (i < c2) {
        s = W2f; d = Wh2; j = i - c1;
      } else {
        s = W3f; d = Wh3; j = i - c2;
      }
      const float4 v = *(const float4*)&s[(size_t)j * 4];
      f16x4 h = {f2h(v.x), f2h(v.y), f2h(v.z), f2h(v.w)};
      *(f16x4*)&d[(size_t)j * 4] = h;
    } else {
      const int j = i - c3;
      *(float4*)&out[(size_t)j * 4] = *(const float4*)&b3[(j & 63) * 4];
    }
  }
}

// ---------------------------------------------------------------------------
// Layers 1-2: C = relu(bn(A[128,K] @ W[128,K]^T)) -> fp16 into H.
// Grid dim3(64,8). R2's proven body: BK=64, 16x16x32, 0 bank conflicts.
__launch_bounds__(256, 4) __global__
void gemm_bn_kernel(const _Float16* __restrict__ A, int K,
                    const _Float16* __restrict__ W,
                    const float* __restrict__ bias,
                    const float* __restrict__ g, const float* __restrict__ be,
                    const float* __restrict__ rm,
                    const float* __restrict__ rv, _Float16* __restrict__ outH,
                    int outOff) {
  __shared__ _Float16 Alds[128 * 64];
  __shared__ _Float16 Blds[128 * 64];

  const int tid = threadIdx.x;
  const int lane = tid & 63;
  const int wave = tid >> 6;          // 0..3
  const int wr = wave >> 1;           // 64-row half
  const int wc = wave & 1;            // 64-col half
  const int row0 = blockIdx.x * 128;  // M block
  const int col0 = blockIdx.y * 128;  // N block
  const int lr = lane >> 3;  // staging: 8 rows x 8 16B-chunks
  const int ls = lane & 7;
  const int lc = ls ^ lr;    // XOR-swizzle
  const int fr = lane & 15;
  const int q = lane >> 4;

  f32x4 acc[4][4] = {};

  for (int k0 = 0; k0 < K; k0 += 64) {
    __syncthreads();
#pragma unroll
    for (int it = 0; it < 4; ++it) {
      const int rl = it * 32 + wave * 8;
      async_cp16(A + (size_t)(row0 + rl + lr) * LDH + k0 + lc * 8,
                 &Alds[rl * 64]);
      async_cp16(W + (size_t)(col0 + rl + lr) * K + k0 + lc * 8,
                 &Blds[rl * 64]);
    }
    __syncthreads();

#pragma unroll
    for (int kq = 0; kq < 2; ++kq) {
      f16x8 av[4], bv[4];
#pragma unroll
      for (int t = 0; t < 4; ++t) {
        const int ra = wr * 64 + t * 16 + fr;
        av[t] = *(const f16x8*)&Alds[ra * 64 + (((q + 4 * kq) ^ (ra & 7)) * 8)];
        const int rb = wc * 64 + t * 16 + fr;
        bv[t] = *(const f16x8*)&Blds[rb * 64 + (((q + 4 * kq) ^ (rb & 7)) * 8)];
      }
#pragma unroll
      for (int tm = 0; tm < 4; ++tm)
#pragma unroll
        for (int tn = 0; tn < 4; ++tn)
          acc[tm][tn] = __builtin_amdgcn_mfma_f32_16x16x32_f16(
              av[tm], bv[tn], acc[tm][tn], 0, 0, 0);
    }
  }

#pragma unroll
  for (int tn = 0; tn < 4; ++tn) {
    const int n = col0 + wc * 64 + tn * 16 + fr;
    const float alpha = g[n] * rsqrtf(rv[n] + 1e-5f);
    const float beta = (bias[n] - rm[n]) * alpha + be[n];
#pragma unroll
    for (int tm = 0; tm < 4; ++tm) {
      const int rbase = row0 + wr * 64 + tm * 16 + q * 4;
#pragma unroll
      for (int r = 0; r < 4; ++r) {
        float v = acc[tm][tn][r] * alpha + beta;
        v = fmaxf(v, 0.0f);
        outH[(size_t)(rbase + r) * LDH + outOff + n] = f2h(v);
      }
    }
  }
}

// ---------------------------------------------------------------------------
// Layer 3: splitK=4, BK=64. Grid dim3(64,8): cb=by&1, ks=by>>1. Partials
// atomicAdd into out (bias pre-applied by L0 side-work). R2's proven body.
__launch_bounds__(256, 4) __global__
void gemm_out_kernel(const _Float16* __restrict__ A,
                     const _Float16* __restrict__ W,
                     float* __restrict__ out) {
  __shared__ _Float16 Alds[128 * 64];
  __shared__ _Float16 Blds[128 * 64];

  const int tid = threadIdx.x;
  const int lane = tid & 63;
  const int wave = tid >> 6;
  const int wr = wave >> 1;
  const int wc = wave & 1;
  const int row0 = blockIdx.x * 128;
  const int cb = blockIdx.y & 1;
  const int ks = blockIdx.y >> 1;
  const int col0 = cb * 128;
  const int k0b = ks * 832;
  const int k0e = k0b + 832;
  const int lr = lane >> 3;
  const int ls = lane & 7;
  const int lc = ls ^ lr;
  const int fr = lane & 15;
  const int q = lane >> 4;
  const int K = 3328;

  f32x4 acc[4][4] = {};

  for (int k0 = k0b; k0 < k0e; k0 += 64) {
    __syncthreads();
#pragma unroll
    for (int it = 0; it < 4; ++it) {
      const int rl = it * 32 + wave * 8;
      async_cp16(A + (size_t)(row0 + rl + lr) * LDH + k0 + lc * 8,
                 &Alds[rl * 64]);
      async_cp16(W + (size_t)(col0 + rl + lr) * K + k0 + lc * 8,
                 &Blds[rl * 64]);
    }
    __syncthreads();

#pragma unroll
    for (int kq = 0; kq < 2; ++kq) {
      f16x8 av[4], bv[4];
#pragma unroll
      for (int t = 0; t < 4; ++t) {
        const int ra = wr * 64 + t * 16 + fr;
        av[t] = *(const f16x8*)&Alds[ra * 64 + (((q + 4 * kq) ^ (ra & 7)) * 8)];
        const int rb = wc * 64 + t * 16 + fr;
        bv[t] = *(const f16x8*)&Blds[rb * 64 + (((q + 4 * kq) ^ (rb & 7)) * 8)];
      }
#pragma unroll
      for (int tm = 0; tm < 4; ++tm)
#pragma unroll
        for (int tn = 0; tn < 4; ++tn)
          acc[tm][tn] = __builtin_amdgcn_mfma_f32_16x16x32_f16(
              av[tm], bv[tn], acc[tm][tn], 0, 0, 0);
    }
  }

#pragma unroll
  for (int tn = 0; tn < 4; ++tn) {
    const int n = col0 + wc * 64 + tn * 16 + fr;
#pragma unroll
    for (int tm = 0; tm < 4; ++tm) {
      const int rbase = row0 + wr * 64 + tm * 16 + q * 4;
#pragma unroll
      for (int r = 0; r < 4; ++r)
        atomicAdd(&out[(size_t)(rbase + r) * 256 + n], acc[tm][tn][r]);
    }
  }
}

// ---------------------------------------------------------------------------
// ragged segment softmax, in place on out[8192][256]; 4 rows/block (1/wave).
__global__ void segsoftmax_kernel(float* __restrict__ out,
                                  const int* __restrict__ segids) {
  __shared__ float vals[4][256];
  __shared__ float red[4][10];
  const int w = threadIdx.x >> 6;
  const int l = threadIdx.x & 63;
  const int row = blockIdx.x * 4 + w;
  float4 v = *(float4*)&out[(size_t)row * 256 + l * 4];
  *(float4*)&vals[w][l * 4] = v;
  __syncthreads();
  if (l < 10) {
    float m = -1e30f;
    for (int j = c_bnd[l]; j < c_bnd[l + 1]; ++j) m = fmaxf(m, vals[w][j]);
    red[w][l] = m;
  }
  __syncthreads();
  const int4 s4 = *(const int4*)&segids[l * 4];
  float4 e;
  e.x = expf(v.x - red[w][s4.x]);
  e.y = expf(v.y - red[w][s4.y]);
  e.z = expf(v.z - red[w][s4.z]);
  e.w = expf(v.w - red[w][s4.w]);
  *(float4*)&vals[w][l * 4] = e;
  __syncthreads();
  if (l < 10) {
    float s = 0.0f;
    for (int j = c_bnd[l]; j < c_bnd[l + 1]; ++j) s += vals[w][j];
    red[w][l] = s;
  }
  __syncthreads();
  float4 o;
  o.x = e.x / red[w][s4.x];
  o.y = e.y / red[w][s4.y];
  o.z = e.z / red[w][s4.z];
  o.w = e.w / red[w][s4.w];
  *(float4*)&out[(size_t)row * 256 + l * 4] = o;
}

// ---------------------------------------------------------------------------
extern "C" void kernel_launch(void* const* d_in, const int* in_sizes, int n_in,
                              void* d_out, int out_size, void* d_ws,
                              size_t ws_size, hipStream_t stream) {
  const float* x = (const float*)d_in[0];
  const float* W0 = (const float*)d_in[1];
  const float* b0 = (const float*)d_in[2];
  const float* g0 = (const float*)d_in[3];
  const float* be0 = (const float*)d_in[4];
  const float* rm0 = (const float*)d_in[5];
  const float* rv0 = (const float*)d_in[6];
  const float* W1 = (const float*)d_in[7];
  const float* b1 = (const float*)d_in[8];
  const float* g1 = (const float*)d_in[9];
  const float* be1 = (const float*)d_in[10];
  const float* rm1 = (const float*)d_in[11];
  const float* rv1 = (const float*)d_in[12];
  const float* W2 = (const float*)d_in[13];
  const float* b2 = (const float*)d_in[14];
  const float* g2 = (const float*)d_in[15];
  const float* be2 = (const float*)d_in[16];
  const float* rm2 = (const float*)d_in[17];
  const float* rv2 = (const float*)d_in[18];
  const float* W3 = (const float*)d_in[19];
  const float* b3 = (const float*)d_in[20];
  const int* seg = (const int*)d_in[21];
  float* out = (float*)d_out;

  // ws (fp16): H[8192*3328] | Wh1 | Wh2 | Wh3  (~63.9 MB)
  _Float16* H = (_Float16*)d_ws;
  size_t off = (size_t)NROWS * LDH;
  _Float16* Wh1 = H + off; off += 1024 * 1280;
  _Float16* Wh2 = H + off; off += 1024 * 2304;
  _Float16* Wh3 = H + off;

  dim3 blk(256);
  l0_kernel<<<dim3(64, 8), blk, 0, stream>>>(
      x, W0, b0, g0, be0, rm0, rv0, W1, W2, W3, b3, H, Wh1, Wh2, Wh3, out);
  gemm_bn_kernel<<<dim3(64, 8), blk, 0, stream>>>(
      H + 2048, 1280, Wh1, b1, g1, be1, rm1, rv1, H, 1024);
  gemm_bn_kernel<<<dim3(64, 8), blk, 0, stream>>>(
      H + 1024, 2304, Wh2, b2, g2, be2, rm2, rv2, H, 0);
  gemm_out_kernel<<<dim3(64, 8), blk, 0, stream>>>(H, Wh3, out);
  segsoftmax_kernel<<<2048, 256, 0, stream>>>(out, seg);
}

// Round 10
// 249.844 us; speedup vs baseline: 1.0611x; 1.0149x over previous
//
#include <hip/hip_runtime.h>
#include <hip/hip_fp16.h>

// ResidualDenoiser: 4 chained GEMMs + BN/ReLU + ragged segment softmax.
// Activations live in one persistent fp16 buffer H[8192][3328] laid out
// [A3 | A2 | A1 | A0=x] so each layer's concatenated input is H + colOff.
//   layer0: in H+3072 (K= 256) -> out cols 2048:3072
//   layer1: in H+2048 (K=1280) -> out cols 1024:2048
//   layer2: in H+1024 (K=2304) -> out cols    0:1024
//   layer3: in H+0    (K=3328) -> splitK=4 atomicAdd fp32 into out (bias
//           pre-applied by prep), then separate segment-softmax dispatch.
// LESSONS (measured):
//  - R4/R5/R6: in-kernel cross-block sync costs 300-450 us on this 8-XCD
//    part — dispatch boundaries ARE the cheap sync (~10 us each).
//  - R7: BK=128 regressed (LDS conflicts). R8: 32x32x16 MFMA regressed
//    (32-row frag reads alias banks). 16x16x32 + BK=64 + XOR swizzle is the
//    only measured 0-conflict config. R9: folding prep into L0 regressed.
//  - R10: 512-thread blocks (8 waves, wave grid 2x4, per-wave 64x32) double
//    resident waves 8->16/CU at fixed grid 512; LDS/staging pattern intact.
// GEMM tile: BM=BN=128, BK=64, 16x16x32 f16 MFMA.

#define LDH 3328
#define NROWS 8192

typedef _Float16 f16x8 __attribute__((ext_vector_type(8)));
typedef _Float16 f16x4 __attribute__((ext_vector_type(4)));
typedef float f32x4 __attribute__((ext_vector_type(4)));

__constant__ int c_bnd[11] = {0, 2, 5, 10, 18, 31, 52, 86, 141, 230, 256};

// async global->LDS, 16B per lane; LDS dest is wave-uniform base + lane*16.
__device__ __forceinline__ void async_cp16(const _Float16* g, _Float16* l) {
  __builtin_amdgcn_global_load_lds(
      (__attribute__((address_space(1))) void*)g,
      (__attribute__((address_space(3))) void*)l, 16, 0, 0);
}

__device__ __forceinline__ _Float16 f2h(float f) { return (_Float16)f; }

// ---------------------------------------------------------------------------
// prep: weights fp32->fp16 (contiguous), x staged into H, out = bias.
__global__ void prep_kernel(const float* __restrict__ s0,
                            const float* __restrict__ s1,
                            const float* __restrict__ s2,
                            const float* __restrict__ s3,
                            const float* __restrict__ x,
                            const float* __restrict__ b3,
                            _Float16* __restrict__ d0,
                            _Float16* __restrict__ d1,
                            _Float16* __restrict__ d2,
                            _Float16* __restrict__ d3,
                            _Float16* __restrict__ H, float* __restrict__ out,
                            int n0, int n1, int n2, int n3, int n4, int n5) {
  int i = blockIdx.x * blockDim.x + threadIdx.x;
  if (i >= n5) return;
  if (i >= n4) {  // out[8192][256] = broadcast bias b3
    const int j = i - n4;
    const int c = (j & 63) * 4;
    *(float4*)&out[(size_t)j * 4] = *(const float4*)&b3[c];
    return;
  }
  if (i >= n3) {  // x[8192,256] -> H[:, 3072:3328]
    const int j = i - n3;
    const int row = j >> 6;
    const int c = (j & 63) * 4;
    const float4 v = *(const float4*)&x[(size_t)j * 4];
    f16x4 h = {f2h(v.x), f2h(v.y), f2h(v.z), f2h(v.w)};
    *(f16x4*)&H[(size_t)row * LDH + 3072 + c] = h;
    return;
  }
  const float* s;
  _Float16* d;
  if (i < n0) {
    s = s0; d = d0;
  } else if (i < n1) {
    s = s1 - (size_t)n0 * 4; d = d1 - (size_t)n0 * 4;
  } else if (i < n2) {
    s = s2 - (size_t)n1 * 4; d = d2 - (size_t)n1 * 4;
  } else {
    s = s3 - (size_t)n2 * 4; d = d3 - (size_t)n2 * 4;
  }
  const float4 v = *(const float4*)&s[(size_t)i * 4];
  f16x4 h = {f2h(v.x), f2h(v.y), f2h(v.z), f2h(v.w)};
  *(f16x4*)&d[(size_t)i * 4] = h;
}

// ---------------------------------------------------------------------------
// Layers 0-2: C = relu(bn(A[128,K] @ W[128,K]^T)) -> fp16 into H.
// Grid dim3(64,8), block 512 (8 waves; wave grid 2x4, per-wave 64x32).
// BK=64 staging + XOR swizzle (0-conflict, R2-proven); 16 waves/CU resident.
__launch_bounds__(512, 4) __global__
void gemm_bn_kernel(const _Float16* __restrict__ A, int K,
                    const _Float16* __restrict__ W,
                    const float* __restrict__ bias,
                    const float* __restrict__ g, const float* __restrict__ be,
                    const float* __restrict__ rm,
                    const float* __restrict__ rv, _Float16* __restrict__ outH,
                    int outOff) {
  __shared__ _Float16 Alds[128 * 64];
  __shared__ _Float16 Blds[128 * 64];

  const int tid = threadIdx.x;
  const int lane = tid & 63;
  const int wave = tid >> 6;          // 0..7
  const int wr = wave >> 2;           // 64-row half
  const int wcq = wave & 3;           // 32-col quarter
  const int row0 = blockIdx.x * 128;  // M block
  const int col0 = blockIdx.y * 128;  // N block
  // staging lane decomposition: 8 rows x 8 chunks(16B) per wave-instruction
  const int lr = lane >> 3;  // row within 8-row group
  const int ls = lane & 7;   // lds slot within row
  const int lc = ls ^ lr;    // XOR-swizzle: global chunk fetched into slot ls
  // fragment lane decomposition (16x16x32 MFMA)
  const int fr = lane & 15;  // m (A) / n (B) index
  const int q = lane >> 4;   // quad: k = q*8 + j

  f32x4 acc[4][2] = {};

  for (int k0 = 0; k0 < K; k0 += 64) {
    __syncthreads();  // previous-iter consumers done before overwrite
#pragma unroll
    for (int it = 0; it < 2; ++it) {
      const int rl = (it * 8 + wave) * 8;  // 16 instrs cover 128 rows
      async_cp16(A + (size_t)(row0 + rl + lr) * LDH + k0 + lc * 8,
                 &Alds[rl * 64]);
      async_cp16(W + (size_t)(col0 + rl + lr) * K + k0 + lc * 8,
                 &Blds[rl * 64]);
    }
    __syncthreads();  // drains vmcnt: staging complete

#pragma unroll
    for (int kq = 0; kq < 2; ++kq) {
      f16x8 av[4], bv[2];
#pragma unroll
      for (int t = 0; t < 4; ++t) {
        const int ra = wr * 64 + t * 16 + fr;
        av[t] = *(const f16x8*)&Alds[ra * 64 + (((q + 4 * kq) ^ (ra & 7)) * 8)];
      }
#pragma unroll
      for (int t = 0; t < 2; ++t) {
        const int rb = wcq * 32 + t * 16 + fr;
        bv[t] = *(const f16x8*)&Blds[rb * 64 + (((q + 4 * kq) ^ (rb & 7)) * 8)];
      }
#pragma unroll
      for (int tm = 0; tm < 4; ++tm)
#pragma unroll
        for (int tn = 0; tn < 2; ++tn)
          acc[tm][tn] = __builtin_amdgcn_mfma_f32_16x16x32_f16(
              av[tm], bv[tn], acc[tm][tn], 0, 0, 0);
    }
  }

  // Epilogue. C/D layout: col = lane&15, row = (lane>>4)*4 + reg.
#pragma unroll
  for (int tn = 0; tn < 2; ++tn) {
    const int n = col0 + wcq * 32 + tn * 16 + fr;
    const float alpha = g[n] * rsqrtf(rv[n] + 1e-5f);
    const float beta = (bias[n] - rm[n]) * alpha + be[n];
#pragma unroll
    for (int tm = 0; tm < 4; ++tm) {
      const int rbase = row0 + wr * 64 + tm * 16 + q * 4;
#pragma unroll
      for (int r = 0; r < 4; ++r) {
        float v = acc[tm][tn][r] * alpha + beta;
        v = fmaxf(v, 0.0f);
        outH[(size_t)(rbase + r) * LDH + outOff + n] = f2h(v);
      }
    }
  }
}

// ---------------------------------------------------------------------------
// Layer 3: splitK=4, BK=64. Grid dim3(64,8): cb=by&1, ks=by>>1. Partials
// atomicAdd into out (bias pre-applied by prep). R2's exact proven body.
__launch_bounds__(256, 4) __global__
void gemm_out_kernel(const _Float16* __restrict__ A,
                     const _Float16* __restrict__ W,
                     float* __restrict__ out) {
  __shared__ _Float16 Alds[128 * 64];
  __shared__ _Float16 Blds[128 * 64];

  const int tid = threadIdx.x;
  const int lane = tid & 63;
  const int wave = tid >> 6;
  const int wr = wave >> 1;
  const int wc = wave & 1;
  const int row0 = blockIdx.x * 128;
  const int cb = blockIdx.y & 1;
  const int ks = blockIdx.y >> 1;
  const int col0 = cb * 128;
  const int k0b = ks * 832;
  const int k0e = k0b + 832;
  const int lr = lane >> 3;
  const int ls = lane & 7;
  const int lc = ls ^ lr;
  const int fr = lane & 15;
  const int q = lane >> 4;
  const int K = 3328;

  f32x4 acc[4][4] = {};

  for (int k0 = k0b; k0 < k0e; k0 += 64) {
    __syncthreads();
#pragma unroll
    for (int it = 0; it < 4; ++it) {
      const int rl = it * 32 + wave * 8;
      async_cp16(A + (size_t)(row0 + rl + lr) * LDH + k0 + lc * 8,
                 &Alds[rl * 64]);
      async_cp16(W + (size_t)(col0 + rl + lr) * K + k0 + lc * 8,
                 &Blds[rl * 64]);
    }
    __syncthreads();

#pragma unroll
    for (int kq = 0; kq < 2; ++kq) {
      f16x8 av[4], bv[4];
#pragma unroll
      for (int t = 0; t < 4; ++t) {
        const int ra = wr * 64 + t * 16 + fr;
        av[t] = *(const f16x8*)&Alds[ra * 64 + (((q + 4 * kq) ^ (ra & 7)) * 8)];
        const int rb = wc * 64 + t * 16 + fr;
        bv[t] = *(const f16x8*)&Blds[rb * 64 + (((q + 4 * kq) ^ (rb & 7)) * 8)];
      }
#pragma unroll
      for (int tm = 0; tm < 4; ++tm)
#pragma unroll
        for (int tn = 0; tn < 4; ++tn)
          acc[tm][tn] = __builtin_amdgcn_mfma_f32_16x16x32_f16(
              av[tm], bv[tn], acc[tm][tn], 0, 0, 0);
    }
  }

#pragma unroll
  for (int tn = 0; tn < 4; ++tn) {
    const int n = col0 + wc * 64 + tn * 16 + fr;
#pragma unroll
    for (int tm = 0; tm < 4; ++tm) {
      const int rbase = row0 + wr * 64 + tm * 16 + q * 4;
#pragma unroll
      for (int r = 0; r < 4; ++r)
        atomicAdd(&out[(size_t)(rbase + r) * 256 + n], acc[tm][tn][r]);
    }
  }
}

// ---------------------------------------------------------------------------
// ragged segment softmax, in place on out[8192][256]; 4 rows/block (1/wave).
__global__ void segsoftmax_kernel(float* __restrict__ out,
                                  const int* __restrict__ segids) {
  __shared__ float vals[4][256];
  __shared__ float red[4][10];
  const int w = threadIdx.x >> 6;
  const int l = threadIdx.x & 63;
  const int row = blockIdx.x * 4 + w;
  float4 v = *(float4*)&out[(size_t)row * 256 + l * 4];
  *(float4*)&vals[w][l * 4] = v;
  __syncthreads();
  if (l < 10) {
    float m = -1e30f;
    for (int j = c_bnd[l]; j < c_bnd[l + 1]; ++j) m = fmaxf(m, vals[w][j]);
    red[w][l] = m;
  }
  __syncthreads();
  const int4 s4 = *(const int4*)&segids[l * 4];
  float4 e;
  e.x = expf(v.x - red[w][s4.x]);
  e.y = expf(v.y - red[w][s4.y]);
  e.z = expf(v.z - red[w][s4.z]);
  e.w = expf(v.w - red[w][s4.w]);
  *(float4*)&vals[w][l * 4] = e;
  __syncthreads();
  if (l < 10) {
    float s = 0.0f;
    for (int j = c_bnd[l]; j < c_bnd[l + 1]; ++j) s += vals[w][j];
    red[w][l] = s;
  }
  __syncthreads();
  float4 o;
  o.x = e.x / red[w][s4.x];
  o.y = e.y / red[w][s4.y];
  o.z = e.z / red[w][s4.z];
  o.w = e.w / red[w][s4.w];
  *(float4*)&out[(size_t)row * 256 + l * 4] = o;
}

// ---------------------------------------------------------------------------
extern "C" void kernel_launch(void* const* d_in, const int* in_sizes, int n_in,
                              void* d_out, int out_size, void* d_ws,
                              size_t ws_size, hipStream_t stream) {
  const float* x = (const float*)d_in[0];
  const float* W0 = (const float*)d_in[1];
  const float* b0 = (const float*)d_in[2];
  const float* g0 = (const float*)d_in[3];
  const float* be0 = (const float*)d_in[4];
  const float* rm0 = (const float*)d_in[5];
  const float* rv0 = (const float*)d_in[6];
  const float* W1 = (const float*)d_in[7];
  const float* b1 = (const float*)d_in[8];
  const float* g1 = (const float*)d_in[9];
  const float* be1 = (const float*)d_in[10];
  const float* rm1 = (const float*)d_in[11];
  const float* rv1 = (const float*)d_in[12];
  const float* W2 = (const float*)d_in[13];
  const float* b2 = (const float*)d_in[14];
  const float* g2 = (const float*)d_in[15];
  const float* be2 = (const float*)d_in[16];
  const float* rm2 = (const float*)d_in[17];
  const float* rv2 = (const float*)d_in[18];
  const float* W3 = (const float*)d_in[19];
  const float* b3 = (const float*)d_in[20];
  const int* seg = (const int*)d_in[21];
  float* out = (float*)d_out;

  // ws (fp16): H[8192*3328] | Wh0 | Wh1 | Wh2 | Wh3  (~64.1 MB)
  _Float16* H = (_Float16*)d_ws;
  size_t off = (size_t)NROWS * LDH;
  _Float16* Wh0 = H + off; off += 1024 * 256;
  _Float16* Wh1 = H + off; off += 1024 * 1280;
  _Float16* Wh2 = H + off; off += 1024 * 2304;
  _Float16* Wh3 = H + off;

  // cumulative float4 counts: W0, W1, W2, W3, x, out-init
  const int n0 = 65536, n1 = n0 + 327680, n2 = n1 + 589824, n3 = n2 + 212992;
  const int n4 = n3 + 524288, n5 = n4 + 524288;
  prep_kernel<<<(n5 + 255) / 256, 256, 0, stream>>>(
      W0, W1, W2, W3, x, b3, Wh0, Wh1, Wh2, Wh3, H, out, n0, n1, n2, n3, n4,
      n5);

  dim3 blk(512);
  gemm_bn_kernel<<<dim3(64, 8), blk, 0, stream>>>(
      H + 3072, 256, Wh0, b0, g0, be0, rm0, rv0, H, 2048);
  gemm_bn_kernel<<<dim3(64, 8), blk, 0, stream>>>(
      H + 2048, 1280, Wh1, b1, g1, be1, rm1, rv1, H, 1024);
  gemm_bn_kernel<<<dim3(64, 8), blk, 0, stream>>>(
      H + 1024, 2304, Wh2, b2, g2, be2, rm2, rv2, H, 0);
  gemm_out_kernel<<<dim3(64, 8), dim3(256), 0, stream>>>(H, Wh3, out);
  segsoftmax_kernel<<<2048, 256, 0, stream>>>(out, seg);
}